// Round 7
// baseline (150.544 us; speedup 1.0000x reference)
//
#include <hip/hip_runtime.h>

#define LOG2E    1.4426950408889634f
#define TWOLOG2E 2.8853900817779268f

#define NBLK 512u

// One fused kernel, 512 blocks x 256 threads, >=2 blocks/CU co-resident
// (LDS 34.3KB, __launch_bounds__(256,2)) so a manual grid barrier is
// deadlock-free. Barrier = single arrival fetch_add + last-arriver RELEASE
// flag store; waiters poll the flag with relaxed atomic LOADS (no RMW spin —
// R6's atomicAdd-poll self-congested the coherence point: 115us of spin).
// Counters/flags are hipMemsetAsync'd to 0 inside the captured graph.
//
// Phase 1: proj   (block = 8 rows of q or k)      -> qp, kp (scaled 2log2e)
// Phase 2: scoreP (block = (kt,qt,b) 32x32 tile)  -> P, Zpart
// Phase 3: pv     (block = (b, 4 q-rows))         -> out

__device__ __forceinline__ void grid_barrier(unsigned* ctr, unsigned* flag)
{
    __syncthreads();
    if (threadIdx.x == 0) {
        __threadfence();                                   // release my writes
        unsigned old = __hip_atomic_fetch_add(ctr, 1u, __ATOMIC_ACQ_REL,
                                              __HIP_MEMORY_SCOPE_AGENT);
        if (old == NBLK - 1u) {
            __hip_atomic_store(flag, 1u, __ATOMIC_RELEASE,
                               __HIP_MEMORY_SCOPE_AGENT);
        } else {
            while (__hip_atomic_load(flag, __ATOMIC_ACQUIRE,
                                     __HIP_MEMORY_SCOPE_AGENT) == 0u)
                __builtin_amdgcn_s_sleep(16);              // ~1k cyc backoff
        }
        __threadfence();                                   // acquire others'
    }
    __syncthreads();
}

__global__ __launch_bounds__(256, 2) void mega_kernel(
    const float* __restrict__ queries, const float* __restrict__ keys,
    const float* __restrict__ values,
    const float* __restrict__ Wq, const float* __restrict__ Wk,
    const float* __restrict__ wv,
    float* __restrict__ out,
    float* __restrict__ qp, float* __restrict__ kp,
    float* __restrict__ P, float* __restrict__ Zpart,
    unsigned* __restrict__ bar)
{
    __shared__ float smem[8576];
    const int t   = threadIdx.x;
    const int bid = blockIdx.x;

    // ======================= Phase 1: projections =======================
    {
        const int isK = bid >= 256;
        const int rowBase = (bid & 255) * 8;
        const float* __restrict__ x = isK ? keys : queries;
        const float* __restrict__ W = isK ? Wk : Wq;
        float* __restrict__ op = isK ? kp : qp;

        float* Wc = smem;          // [128][37] padded chunk (32 d-cols)
        float* xs = smem + 4736;   // [8][128]

        ((float4*)xs)[t] = ((const float4*)(x + (size_t)rowBase * 128))[t];

        const int h = t & 127;
        const int rhalf = t >> 7;          // 0: rows 0-3, 1: rows 4-7
        float acc[4] = {0.f, 0.f, 0.f, 0.f};

        for (int c = 0; c < 4; ++c) {      // 4 chunks of 32 d-columns
            __syncthreads();               // protect Wc reuse (covers xs stage)
            #pragma unroll
            for (int j = 0; j < 4; ++j) {  // stage 128x32 chunk coalesced
                int i  = t + j * 256;      // float4 index 0..1023
                int r  = i >> 3;           // W row 0..127
                int c4 = i & 7;            // float4 within chunk
                float4 v = *(const float4*)(W + (size_t)r * 128 + c * 32 + c4 * 4);
                *(float4*)&Wc[r * 37 + c4 * 4] = v;
            }
            __syncthreads();
            #pragma unroll
            for (int d4 = 0; d4 < 8; ++d4) {
                float4 w = *(const float4*)&Wc[h * 37 + d4 * 4];  // odd stride
                #pragma unroll
                for (int r = 0; r < 4; ++r) {
                    float4 xv = *(const float4*)&xs[(rhalf * 4 + r) * 128 + c * 32 + d4 * 4];
                    acc[r] = fmaf(xv.x, w.x, acc[r]);
                    acc[r] = fmaf(xv.y, w.y, acc[r]);
                    acc[r] = fmaf(xv.z, w.z, acc[r]);
                    acc[r] = fmaf(xv.w, w.w, acc[r]);
                }
            }
        }
        #pragma unroll
        for (int r = 0; r < 4; ++r)        // coalesced dword stores
            op[(size_t)(rowBase + rhalf * 4 + r) * 128 + h] = acc[r] * TWOLOG2E;
    }

    grid_barrier(bar, bar + 16);

    // ======================= Phase 2: P + Zpart =========================
    {
        const int kt = bid & 7, qt = (bid >> 3) & 7, b = bid >> 6;

        float* qs    = smem;           // [32][130]
        float* ks_   = smem + 4160;    // [32][130]
        float* w2s   = smem + 8320;    // [128]  = -2*wv
        float* part2 = smem + 8448;    // [4][32]

        const float4* qsrc = (const float4*)(qp + (size_t)(b * 256 + qt * 32) * 128);
        const float4* ksrc = (const float4*)(kp + (size_t)(b * 256 + kt * 32) * 128);
        {
            int r = t >> 3, c = (t & 7) * 16;
            #pragma unroll
            for (int j = 0; j < 4; ++j) {
                float4 v  = qsrc[t * 4 + j];
                *(float4*)&qs[r * 130 + c + j * 4] = v;
                float4 v2 = ksrc[t * 4 + j];
                *(float4*)&ks_[r * 130 + c + j * 4] = v2;
            }
            if (t < 32) {
                float4 w = ((const float4*)wv)[t];
                *(float4*)&w2s[t * 4] = make_float4(-2.f * w.x, -2.f * w.y,
                                                    -2.f * w.z, -2.f * w.w);
            }
        }
        __syncthreads();

        float wsum = 0.f;
        #pragma unroll 8
        for (int i = 0; i < 32; ++i) {
            float4 w = *(const float4*)&w2s[i * 4];
            wsum += (w.x + w.y) + (w.z + w.w);
        }
        wsum *= -0.5f;

        const int lk = (t & 15) * 2;
        const int lq = (t >> 4) * 2;

        float a00 = 0.f, a01 = 0.f, a10 = 0.f, a11 = 0.f;

        #pragma unroll 4
        for (int h = 0; h < 128; h += 4) {
            float4 w4 = *(const float4*)&w2s[h];
            float4 qa = *(const float4*)&qs[lq * 130 + h];
            float4 qb = *(const float4*)&qs[(lq + 1) * 130 + h];
            float4 ka = *(const float4*)&ks_[lk * 130 + h];
            float4 kb = *(const float4*)&ks_[(lk + 1) * 130 + h];
            const float wj[4]  = {w4.x, w4.y, w4.z, w4.w};
            const float qaj[4] = {qa.x, qa.y, qa.z, qa.w};
            const float qbj[4] = {qb.x, qb.y, qb.z, qb.w};
            const float kaj[4] = {ka.x, ka.y, ka.z, ka.w};
            const float kbj[4] = {kb.x, kb.y, kb.z, kb.w};
            #pragma unroll
            for (int j = 0; j < 4; ++j) {
                float r00 = __builtin_amdgcn_rcpf(__builtin_amdgcn_exp2f(qaj[j] + kaj[j]) + 1.0f);
                float r01 = __builtin_amdgcn_rcpf(__builtin_amdgcn_exp2f(qaj[j] + kbj[j]) + 1.0f);
                float r10 = __builtin_amdgcn_rcpf(__builtin_amdgcn_exp2f(qbj[j] + kaj[j]) + 1.0f);
                float r11 = __builtin_amdgcn_rcpf(__builtin_amdgcn_exp2f(qbj[j] + kbj[j]) + 1.0f);
                a00 = fmaf(wj[j], r00, a00);
                a01 = fmaf(wj[j], r01, a01);
                a10 = fmaf(wj[j], r10, a10);
                a11 = fmaf(wj[j], r11, a11);
            }
        }

        float p00 = __builtin_amdgcn_exp2f((a00 + wsum) * LOG2E);
        float p01 = __builtin_amdgcn_exp2f((a01 + wsum) * LOG2E);
        float p10 = __builtin_amdgcn_exp2f((a10 + wsum) * LOG2E);
        float p11 = __builtin_amdgcn_exp2f((a11 + wsum) * LOG2E);

        const int q = qt * 32 + lq;
        const int k = kt * 32 + lk;
        *(float2*)&P[((size_t)(b * 256 + q)) * 256 + k]     = make_float2(p00, p01);
        *(float2*)&P[((size_t)(b * 256 + q + 1)) * 256 + k] = make_float2(p10, p11);

        float sa = p00 + p10;
        float sb = p01 + p11;
        sa += __shfl_xor(sa, 16, 64);
        sa += __shfl_xor(sa, 32, 64);
        sb += __shfl_xor(sb, 16, 64);
        sb += __shfl_xor(sb, 32, 64);
        const int wid = t >> 6;
        if ((t & 63) < 16) {
            part2[wid * 32 + lk]     = sa;
            part2[wid * 32 + lk + 1] = sb;
        }
        __syncthreads();
        if (t < 32) {
            float z = part2[t] + part2[32 + t] + part2[64 + t] + part2[96 + t];
            Zpart[(size_t)b * 2048 + qt * 256 + kt * 32 + t] = z;
        }
    }

    grid_barrier(bar + 32, bar + 48);

    // ======================= Phase 3: PV ================================
    {
        const int b  = bid >> 6;
        const int q0 = (bid & 63) * 4;

        float* ps  = smem;          // [4][260]
        float* red = smem + 1040;   // [4 waves][4 q][128 d]

        // p[q][k] = P * (1/Z)  (4 k per thread)
        {
            const int q = t >> 6;
            const int k = (t & 63) * 4;
            const float* zb = Zpart + (size_t)b * 2048 + k;
            float4 z = make_float4(0.f, 0.f, 0.f, 0.f);
            #pragma unroll
            for (int qt = 0; qt < 8; ++qt) {
                float4 a = *(const float4*)(zb + qt * 256);
                z.x += a.x; z.y += a.y; z.z += a.z; z.w += a.w;
            }
            const float* prow = P + ((size_t)(b * 256 + q0 + q)) * 256 + k;
            float4 s = *(const float4*)prow;
            float4 r;
            r.x = s.x * __builtin_amdgcn_rcpf(z.x);
            r.y = s.y * __builtin_amdgcn_rcpf(z.y);
            r.z = s.z * __builtin_amdgcn_rcpf(z.z);
            r.w = s.w * __builtin_amdgcn_rcpf(z.w);
            *(float4*)&ps[q * 260 + k] = r;
        }
        __syncthreads();

        const int wid  = t >> 6;    // k-slice owner: kk in [wid*64, wid*64+64)
        const int lane = t & 63;    // d = lane*2, lane*2+1
        const float* vb = values + (size_t)b * 256 * 128 + lane * 2;

        float ax[4] = {0.f, 0.f, 0.f, 0.f};
        float ay[4] = {0.f, 0.f, 0.f, 0.f};

        for (int kk4 = wid * 16; kk4 < wid * 16 + 16; ++kk4) {
            float4 p0 = *(const float4*)&ps[0 * 260 + kk4 * 4];
            float4 p1 = *(const float4*)&ps[1 * 260 + kk4 * 4];
            float4 p2 = *(const float4*)&ps[2 * 260 + kk4 * 4];
            float4 p3 = *(const float4*)&ps[3 * 260 + kk4 * 4];
            #pragma unroll
            for (int u = 0; u < 4; ++u) {
                int kk = kk4 * 4 + u;
                float2 v = *(const float2*)(vb + (size_t)kk * 128);
                float f0 = (&p0.x)[u], f1 = (&p1.x)[u], f2 = (&p2.x)[u], f3 = (&p3.x)[u];
                ax[0] = fmaf(f0, v.x, ax[0]); ay[0] = fmaf(f0, v.y, ay[0]);
                ax[1] = fmaf(f1, v.x, ax[1]); ay[1] = fmaf(f1, v.y, ay[1]);
                ax[2] = fmaf(f2, v.x, ax[2]); ay[2] = fmaf(f2, v.y, ay[2]);
                ax[3] = fmaf(f3, v.x, ax[3]); ay[3] = fmaf(f3, v.y, ay[3]);
            }
        }

        #pragma unroll
        for (int q = 0; q < 4; ++q)
            *(float2*)&red[wid * 512 + q * 128 + lane * 2] = make_float2(ax[q], ay[q]);
        __syncthreads();

        {
            const int j = t * 2;            // output index: q = j>>7, d = j&127
            float2 s = make_float2(0.f, 0.f);
            #pragma unroll
            for (int w = 0; w < 4; ++w) {
                float2 r = *(const float2*)&red[w * 512 + j];
                s.x += r.x; s.y += r.y;
            }
            const int q = j >> 7, d = j & 127;
            *(float2*)&out[((size_t)(b * 256 + q0 + q)) * 128 + d] = s;
        }
    }
}

// ---------------------------------------------------------------------------
extern "C" void kernel_launch(void* const* d_in, const int* in_sizes, int n_in,
                              void* d_out, int out_size, void* d_ws, size_t ws_size,
                              hipStream_t stream)
{
    const float* queries = (const float*)d_in[0];  // (8,256,128)
    const float* keys    = (const float*)d_in[1];  // (8,256,128)
    const float* values  = (const float*)d_in[2];  // (8,256,128)
    const float* Wq      = (const float*)d_in[3];  // (128,128)
    const float* Wk      = (const float*)d_in[4];  // (128,128)
    const float* wv      = (const float*)d_in[5];  // (128,)
    float* out = (float*)d_out;                    // (8,256,128)

    float* ws = (float*)d_ws;
    float* qp    = ws;                   // 262144 floats (scaled by 2log2e)
    float* kp    = ws + 262144;          // 262144 floats
    float* P     = ws + 524288;          // 524288 floats  exp(s)
    float* Zpart = ws + 1048576;         // 16384 floats
    unsigned* bar = (unsigned*)(ws + 1048576 + 16384);  // ctr/flag pairs, 64B apart

    // reset barrier counters/flags inside the captured graph (deterministic)
    hipMemsetAsync(bar, 0, 64 * sizeof(unsigned), stream);

    mega_kernel<<<NBLK, 256, 0, stream>>>(queries, keys, values, Wq, Wk, wv,
                                          out, qp, kp, P, Zpart, bar);
}

// Round 8
// 47.022 us; speedup vs baseline: 3.2015x; 3.2015x over previous
//
#include <hip/hip_runtime.h>

#define LOG2E    1.4426950408889634f
#define TWOLOG2E 2.8853900817779268f

// ---------------------------------------------------------------------------
// Kernel 1: projections  qp = (queries @ Wq^T) * 2log2e, kp likewise.
// W staged in 32-column chunks into XOR-swizzled LDS (bank-conflict-free,
// aligned), so global W reads are coalesced and the per-lane row reads are
// ds_read_b128. grid 512 (256 q + 256 k blocks), 256 threads, 8 rows/block.
// ---------------------------------------------------------------------------
__global__ __launch_bounds__(256) void proj_kernel(
    const float* __restrict__ queries, const float* __restrict__ keys,
    const float* __restrict__ Wq, const float* __restrict__ Wk,
    float* __restrict__ qp, float* __restrict__ kp)
{
    __shared__ float Wc[128 * 32];   // 16 KB, XOR-swizzled chunk (32 d-cols)
    __shared__ float xs[8 * 128];    // 4 KB
    const int isK = blockIdx.x >= 256;
    const int rowBase = (blockIdx.x & 255) * 8;
    const float* __restrict__ x = isK ? keys : queries;
    const float* __restrict__ W = isK ? Wk : Wq;
    float* __restrict__ op = isK ? kp : qp;
    const int t = threadIdx.x;

    // stage 8x128 x-rows (contiguous, coalesced)
    ((float4*)xs)[t] = ((const float4*)(x + (size_t)rowBase * 128))[t];

    const int h  = t & 127;          // output hidden index (W row)
    const int rt = t >> 7;           // 0: rows 0-3, 1: rows 4-7
    float acc[4] = {0.f, 0.f, 0.f, 0.f};

    for (int c = 0; c < 4; ++c) {    // 4 chunks of 32 d-columns
        __syncthreads();             // protect Wc reuse (also covers xs stage)
        #pragma unroll
        for (int j = 0; j < 4; ++j) {          // stage 128x32 chunk, coalesced
            int i  = t + j * 256;              // float4 index 0..1023
            int r  = i >> 3;                   // W row 0..127
            int c4 = i & 7;                    // float4-within-chunk
            float4 v = *(const float4*)(W + (size_t)r * 128 + c * 32 + c4 * 4);
            *(float4*)&Wc[r * 32 + ((c4 ^ (r & 7)) << 2)] = v;   // swizzle
        }
        __syncthreads();
        #pragma unroll
        for (int j = 0; j < 8; ++j) {
            float4 w = *(const float4*)&Wc[h * 32 + ((j ^ (h & 7)) << 2)];
            #pragma unroll
            for (int r = 0; r < 4; ++r) {
                float4 xv = *(const float4*)&xs[(rt * 4 + r) * 128 + c * 32 + j * 4];
                acc[r] = fmaf(xv.x, w.x, acc[r]);
                acc[r] = fmaf(xv.y, w.y, acc[r]);
                acc[r] = fmaf(xv.z, w.z, acc[r]);
                acc[r] = fmaf(xv.w, w.w, acc[r]);
            }
        }
    }
    #pragma unroll
    for (int r = 0; r < 4; ++r)      // coalesced dword stores
        op[(size_t)(rowBase + rt * 4 + r) * 128 + h] = acc[r] * TWOLOG2E;
}

// ---------------------------------------------------------------------------
// Kernel 2: P[b][q][k] = exp(sum_h wv[h]*tanh(q+k)) and column partial sums
// Zpart[b][qt][k] = sum_{q in tile} P.   w*tanh(x) = w + (-2w)*rcp(e^2x + 1)
// grid (K/32=8, Q/32=8, B=8) = 512 blocks, 256 threads, 2q x 2k per thread
// ---------------------------------------------------------------------------
#define LDP 130

__global__ __launch_bounds__(256) void scoreP_kernel(
    const float* __restrict__ qp, const float* __restrict__ kp,
    const float* __restrict__ wv, float* __restrict__ P,
    float* __restrict__ Zpart)
{
    __shared__ float qs[32 * LDP];
    __shared__ float ks_[32 * LDP];
    __shared__ float w2s[128];          // -2 * wv
    __shared__ float part2[4][32];      // per-wave column partials

    const int kt = blockIdx.x, qt = blockIdx.y, b = blockIdx.z;
    const int t = threadIdx.x;

    const float4* qsrc = (const float4*)(qp + (size_t)(b * 256 + qt * 32) * 128);
    const float4* ksrc = (const float4*)(kp + (size_t)(b * 256 + kt * 32) * 128);
    {
        int r = t >> 3, c = (t & 7) * 16;
        #pragma unroll
        for (int j = 0; j < 4; ++j) {
            float4 v  = qsrc[t * 4 + j];
            *(float4*)&qs[r * LDP + c + j * 4] = v;
            float4 v2 = ksrc[t * 4 + j];
            *(float4*)&ks_[r * LDP + c + j * 4] = v2;
        }
        if (t < 32) {
            float4 w = ((const float4*)wv)[t];
            *(float4*)&w2s[t * 4] = make_float4(-2.f * w.x, -2.f * w.y,
                                                -2.f * w.z, -2.f * w.w);
        }
    }
    __syncthreads();

    // wsum = sum_h wv[h] = -0.5 * sum_h w2s[h]  (broadcast LDS reads)
    float wsum = 0.f;
    #pragma unroll 8
    for (int i = 0; i < 32; ++i) {
        float4 w = *(const float4*)&w2s[i * 4];
        wsum += (w.x + w.y) + (w.z + w.w);
    }
    wsum *= -0.5f;

    const int lk = (t & 15) * 2;
    const int lq = (t >> 4) * 2;

    float a00 = 0.f, a01 = 0.f, a10 = 0.f, a11 = 0.f;

    #pragma unroll 4
    for (int h = 0; h < 128; h += 4) {
        float4 w4 = *(const float4*)&w2s[h];
        float4 qa = *(const float4*)&qs[lq * LDP + h];
        float4 qb = *(const float4*)&qs[(lq + 1) * LDP + h];
        float4 ka = *(const float4*)&ks_[lk * LDP + h];
        float4 kb = *(const float4*)&ks_[(lk + 1) * LDP + h];
        const float wj[4]  = {w4.x, w4.y, w4.z, w4.w};
        const float qaj[4] = {qa.x, qa.y, qa.z, qa.w};
        const float qbj[4] = {qb.x, qb.y, qb.z, qb.w};
        const float kaj[4] = {ka.x, ka.y, ka.z, ka.w};
        const float kbj[4] = {kb.x, kb.y, kb.z, kb.w};
        #pragma unroll
        for (int j = 0; j < 4; ++j) {
            float r00 = __builtin_amdgcn_rcpf(__builtin_amdgcn_exp2f(qaj[j] + kaj[j]) + 1.0f);
            float r01 = __builtin_amdgcn_rcpf(__builtin_amdgcn_exp2f(qaj[j] + kbj[j]) + 1.0f);
            float r10 = __builtin_amdgcn_rcpf(__builtin_amdgcn_exp2f(qbj[j] + kaj[j]) + 1.0f);
            float r11 = __builtin_amdgcn_rcpf(__builtin_amdgcn_exp2f(qbj[j] + kbj[j]) + 1.0f);
            a00 = fmaf(wj[j], r00, a00);
            a01 = fmaf(wj[j], r01, a01);
            a10 = fmaf(wj[j], r10, a10);
            a11 = fmaf(wj[j], r11, a11);
        }
    }

    // s = wsum + acc; p = exp(s) = exp2(s * log2e)
    float p00 = __builtin_amdgcn_exp2f((a00 + wsum) * LOG2E);
    float p01 = __builtin_amdgcn_exp2f((a01 + wsum) * LOG2E);
    float p10 = __builtin_amdgcn_exp2f((a10 + wsum) * LOG2E);
    float p11 = __builtin_amdgcn_exp2f((a11 + wsum) * LOG2E);

    const int q = qt * 32 + lq;
    const int k = kt * 32 + lk;
    *(float2*)&P[((size_t)(b * 256 + q)) * 256 + k]     = make_float2(p00, p01);
    *(float2*)&P[((size_t)(b * 256 + q + 1)) * 256 + k] = make_float2(p10, p11);

    // column partial sums over this tile's 32 q rows: shuffle over the 4
    // lq-groups within each wave, then 4 waves combine through tiny LDS.
    float sa = p00 + p10;           // column lk
    float sb = p01 + p11;           // column lk+1
    sa += __shfl_xor(sa, 16, 64);
    sa += __shfl_xor(sa, 32, 64);
    sb += __shfl_xor(sb, 16, 64);
    sb += __shfl_xor(sb, 32, 64);
    const int wid = t >> 6;
    if ((t & 63) < 16) {
        part2[wid][lk]     = sa;
        part2[wid][lk + 1] = sb;
    }
    __syncthreads();
    if (t < 32) {
        float z = part2[0][t] + part2[1][t] + part2[2][t] + part2[3][t];
        Zpart[(size_t)b * 2048 + qt * 256 + kt * 32 + t] = z;
    }
}

// ---------------------------------------------------------------------------
// Kernel 3: out[b][q][d] = sum_k P[b,q,k] * c[b,k] * v[b,k,d],
//           c[b,k] = 1 / sum_qt Zpart[b][qt][k]
// grid B*(Q/4) = 512 blocks, 256 threads = 4 q-rows x 64 d-threads (float2)
// ---------------------------------------------------------------------------
__global__ __launch_bounds__(256) void pv_kernel(
    const float* __restrict__ P, const float* __restrict__ Zpart,
    const float* __restrict__ values, float* __restrict__ out)
{
    __shared__ float ps[4][260];
    const int b  = blockIdx.x >> 6;
    const int q0 = (blockIdx.x & 63) * 4;
    const int t  = threadIdx.x;

    // phase A: p[q][k] = P * c for 4 q-rows x 256 k  (4 k per thread)
    {
        const int q  = t >> 6;          // 0..3
        const int k  = (t & 63) * 4;    // 0..252
        const float* zb = Zpart + (size_t)b * 2048 + k;
        float4 z = make_float4(0.f, 0.f, 0.f, 0.f);
        #pragma unroll
        for (int qt = 0; qt < 8; ++qt) {
            float4 a = *(const float4*)(zb + qt * 256);
            z.x += a.x; z.y += a.y; z.z += a.z; z.w += a.w;
        }
        const float* prow = P + ((size_t)(b * 256 + q0 + q)) * 256 + k;
        float4 s = *(const float4*)(prow);
        float4 r;
        r.x = s.x * __builtin_amdgcn_rcpf(z.x);
        r.y = s.y * __builtin_amdgcn_rcpf(z.y);
        r.z = s.z * __builtin_amdgcn_rcpf(z.z);
        r.w = s.w * __builtin_amdgcn_rcpf(z.w);
        *(float4*)&ps[q][k] = r;
    }
    __syncthreads();

    const int q  = t >> 6;     // 0..3  (whole wave shares q)
    const int d2 = t & 63;     // d = d2*2
    const float* vcol = values + (size_t)b * 256 * 128 + d2 * 2;

    float ax = 0.f, ay = 0.f;
    #pragma unroll 8
    for (int kk = 0; kk < 256; ++kk) {
        float p = ps[q][kk];
        float2 v = *(const float2*)(vcol + (size_t)kk * 128);
        ax = fmaf(p, v.x, ax);
        ay = fmaf(p, v.y, ay);
    }

    float* o = out + ((size_t)(b * 256 + q0 + q)) * 128 + d2 * 2;
    *(float2*)o = make_float2(ax, ay);
}

// ---------------------------------------------------------------------------
extern "C" void kernel_launch(void* const* d_in, const int* in_sizes, int n_in,
                              void* d_out, int out_size, void* d_ws, size_t ws_size,
                              hipStream_t stream)
{
    const float* queries = (const float*)d_in[0];  // (8,256,128)
    const float* keys    = (const float*)d_in[1];  // (8,256,128)
    const float* values  = (const float*)d_in[2];  // (8,256,128)
    const float* Wq      = (const float*)d_in[3];  // (128,128)
    const float* Wk      = (const float*)d_in[4];  // (128,128)
    const float* wv      = (const float*)d_in[5];  // (128,)
    float* out = (float*)d_out;                    // (8,256,128)

    float* ws = (float*)d_ws;
    float* qp    = ws;                   // 262144 floats (scaled by 2log2e)
    float* kp    = ws + 262144;          // 262144 floats
    float* P     = ws + 524288;          // 524288 floats  exp(s)
    float* Zpart = ws + 1048576;         // 8*8*256 = 16384 floats

    proj_kernel<<<512, 256, 0, stream>>>(queries, keys, Wq, Wk, qp, kp);
    scoreP_kernel<<<dim3(8, 8, 8), 256, 0, stream>>>(qp, kp, wv, P, Zpart);
    pv_kernel<<<512, 256, 0, stream>>>(P, Zpart, values, out);
}

// Round 9
// 40.245 us; speedup vs baseline: 3.7407x; 1.1684x over previous
//
#include <hip/hip_runtime.h>

#define LOG2E    1.4426950408889634f
#define TWOLOG2E 2.8853900817779268f

// ---------------------------------------------------------------------------
// Kernel 0: transpose Wq, Wk (128x128) -> WqT, WkT so proj's per-lane W reads
// are coalesced. 32 blocks x 256 threads, 32x32 LDS tiles, both sides coalesced.
// ---------------------------------------------------------------------------
__global__ __launch_bounds__(256) void transposeW_kernel(
    const float* __restrict__ Wq, const float* __restrict__ Wk,
    float* __restrict__ WqT, float* __restrict__ WkT)
{
    __shared__ float tile[32][33];
    const int m   = blockIdx.x >> 4;            // 0: Wq, 1: Wk
    const int tid = blockIdx.x & 15;            // 4x4 tiles of 32x32
    const int r0 = (tid >> 2) * 32, c0 = (tid & 3) * 32;
    const float* __restrict__ W  = m ? Wk  : Wq;
    float* __restrict__       WT = m ? WkT : WqT;
    const int t = threadIdx.x;

    {   // read 32x32 tile, coalesced float4 rows
        int r = t >> 3, c4 = (t & 7) * 4;
        float4 v = *(const float4*)(W + (size_t)(r0 + r) * 128 + c0 + c4);
        tile[r][c4 + 0] = v.x; tile[r][c4 + 1] = v.y;
        tile[r][c4 + 2] = v.z; tile[r][c4 + 3] = v.w;
    }
    __syncthreads();
    {   // write transposed, coalesced float4 rows of WT
        int c = t >> 3, r4 = (t & 7) * 4;
        float4 v = make_float4(tile[r4 + 0][c], tile[r4 + 1][c],
                               tile[r4 + 2][c], tile[r4 + 3][c]);
        *(float4*)(WT + (size_t)(c0 + c) * 128 + r0 + r4) = v;
    }
}

// ---------------------------------------------------------------------------
// Kernel 1: projections  qp = (queries @ Wq^T) * 2log2e, kp likewise.
// Reads WT[d][h] with h = lane -> every W load is one coalesced 512B
// transaction (fixes the 64-way divergent W reads that cost ~18us).
// grid 512 (256 q + 256 k blocks), 256 threads, 8 rows/block.
// ---------------------------------------------------------------------------
__global__ __launch_bounds__(256) void proj_kernel(
    const float* __restrict__ queries, const float* __restrict__ keys,
    const float* __restrict__ WqT, const float* __restrict__ WkT,
    float* __restrict__ qp, float* __restrict__ kp)
{
    __shared__ float xs[8 * 128];    // 4 KB
    const int isK = blockIdx.x >= 256;
    const int rowBase = (blockIdx.x & 255) * 8;
    const float* __restrict__ x  = isK ? keys : queries;
    const float* __restrict__ WT = isK ? WkT : WqT;
    float* __restrict__ op = isK ? kp : qp;
    const int t = threadIdx.x;

    ((float4*)xs)[t] = ((const float4*)(x + (size_t)rowBase * 128))[t];
    __syncthreads();

    const int h  = t & 127;          // output hidden index (lane -> coalesced)
    const int rh = t >> 7;           // 0: rows 0-3, 1: rows 4-7
    float acc[4] = {0.f, 0.f, 0.f, 0.f};

    #pragma unroll 4
    for (int d4 = 0; d4 < 32; ++d4) {
        float w0 = WT[(size_t)(d4 * 4 + 0) * 128 + h];
        float w1 = WT[(size_t)(d4 * 4 + 1) * 128 + h];
        float w2 = WT[(size_t)(d4 * 4 + 2) * 128 + h];
        float w3 = WT[(size_t)(d4 * 4 + 3) * 128 + h];
        #pragma unroll
        for (int r = 0; r < 4; ++r) {
            float4 xv = *(const float4*)&xs[(rh * 4 + r) * 128 + d4 * 4];
            acc[r] = fmaf(xv.x, w0, acc[r]);
            acc[r] = fmaf(xv.y, w1, acc[r]);
            acc[r] = fmaf(xv.z, w2, acc[r]);
            acc[r] = fmaf(xv.w, w3, acc[r]);
        }
    }
    #pragma unroll
    for (int r = 0; r < 4; ++r)      // coalesced dword stores
        op[(size_t)(rowBase + rh * 4 + r) * 128 + h] = acc[r] * TWOLOG2E;
}

// ---------------------------------------------------------------------------
// Kernel 2: P[b][q][k] = exp(sum_h wv[h]*tanh(q+k)) and column partial sums
// Zpart[b][qt][k] = sum_{q in tile} P.   w*tanh(x) = w + (-2w)*rcp(e^2x + 1)
// grid (K/32=8, Q/32=8, B=8) = 512 blocks, 256 threads, 2q x 2k per thread
// ---------------------------------------------------------------------------
#define LDP 130

__global__ __launch_bounds__(256) void scoreP_kernel(
    const float* __restrict__ qp, const float* __restrict__ kp,
    const float* __restrict__ wv, float* __restrict__ P,
    float* __restrict__ Zpart)
{
    __shared__ float qs[32 * LDP];
    __shared__ float ks_[32 * LDP];
    __shared__ float w2s[128];          // -2 * wv
    __shared__ float part2[4][32];      // per-wave column partials

    const int kt = blockIdx.x, qt = blockIdx.y, b = blockIdx.z;
    const int t = threadIdx.x;

    const float4* qsrc = (const float4*)(qp + (size_t)(b * 256 + qt * 32) * 128);
    const float4* ksrc = (const float4*)(kp + (size_t)(b * 256 + kt * 32) * 128);
    {
        int r = t >> 3, c = (t & 7) * 16;
        #pragma unroll
        for (int j = 0; j < 4; ++j) {
            float4 v  = qsrc[t * 4 + j];
            *(float4*)&qs[r * LDP + c + j * 4] = v;
            float4 v2 = ksrc[t * 4 + j];
            *(float4*)&ks_[r * LDP + c + j * 4] = v2;
        }
        if (t < 32) {
            float4 w = ((const float4*)wv)[t];
            *(float4*)&w2s[t * 4] = make_float4(-2.f * w.x, -2.f * w.y,
                                                -2.f * w.z, -2.f * w.w);
        }
    }
    __syncthreads();

    float wsum = 0.f;
    #pragma unroll 8
    for (int i = 0; i < 32; ++i) {
        float4 w = *(const float4*)&w2s[i * 4];
        wsum += (w.x + w.y) + (w.z + w.w);
    }
    wsum *= -0.5f;

    const int lk = (t & 15) * 2;
    const int lq = (t >> 4) * 2;

    float a00 = 0.f, a01 = 0.f, a10 = 0.f, a11 = 0.f;

    #pragma unroll 4
    for (int h = 0; h < 128; h += 4) {
        float4 w4 = *(const float4*)&w2s[h];
        float4 qa = *(const float4*)&qs[lq * LDP + h];
        float4 qb = *(const float4*)&qs[(lq + 1) * LDP + h];
        float4 ka = *(const float4*)&ks_[lk * LDP + h];
        float4 kb = *(const float4*)&ks_[(lk + 1) * LDP + h];
        const float wj[4]  = {w4.x, w4.y, w4.z, w4.w};
        const float qaj[4] = {qa.x, qa.y, qa.z, qa.w};
        const float qbj[4] = {qb.x, qb.y, qb.z, qb.w};
        const float kaj[4] = {ka.x, ka.y, ka.z, ka.w};
        const float kbj[4] = {kb.x, kb.y, kb.z, kb.w};
        #pragma unroll
        for (int j = 0; j < 4; ++j) {
            float r00 = __builtin_amdgcn_rcpf(__builtin_amdgcn_exp2f(qaj[j] + kaj[j]) + 1.0f);
            float r01 = __builtin_amdgcn_rcpf(__builtin_amdgcn_exp2f(qaj[j] + kbj[j]) + 1.0f);
            float r10 = __builtin_amdgcn_rcpf(__builtin_amdgcn_exp2f(qbj[j] + kaj[j]) + 1.0f);
            float r11 = __builtin_amdgcn_rcpf(__builtin_amdgcn_exp2f(qbj[j] + kbj[j]) + 1.0f);
            a00 = fmaf(wj[j], r00, a00);
            a01 = fmaf(wj[j], r01, a01);
            a10 = fmaf(wj[j], r10, a10);
            a11 = fmaf(wj[j], r11, a11);
        }
    }

    float p00 = __builtin_amdgcn_exp2f((a00 + wsum) * LOG2E);
    float p01 = __builtin_amdgcn_exp2f((a01 + wsum) * LOG2E);
    float p10 = __builtin_amdgcn_exp2f((a10 + wsum) * LOG2E);
    float p11 = __builtin_amdgcn_exp2f((a11 + wsum) * LOG2E);

    const int q = qt * 32 + lq;
    const int k = kt * 32 + lk;
    *(float2*)&P[((size_t)(b * 256 + q)) * 256 + k]     = make_float2(p00, p01);
    *(float2*)&P[((size_t)(b * 256 + q + 1)) * 256 + k] = make_float2(p10, p11);

    float sa = p00 + p10;
    float sb = p01 + p11;
    sa += __shfl_xor(sa, 16, 64);
    sa += __shfl_xor(sa, 32, 64);
    sb += __shfl_xor(sb, 16, 64);
    sb += __shfl_xor(sb, 32, 64);
    const int wid = t >> 6;
    if ((t & 63) < 16) {
        part2[wid][lk]     = sa;
        part2[wid][lk + 1] = sb;
    }
    __syncthreads();
    if (t < 32) {
        float z = part2[0][t] + part2[1][t] + part2[2][t] + part2[3][t];
        Zpart[(size_t)b * 2048 + qt * 256 + kt * 32 + t] = z;
    }
}

// ---------------------------------------------------------------------------
// Kernel 3: out[b][q][d] = sum_k P[b,q,k]*c[b,k]*v[b,k,d], c = 1/sum Zpart.
// grid B*(Q/4) = 512 blocks, 256 threads. Waves split the k range (64 k each)
// then tree-combine in LDS: V read once per block -> L2 traffic 268MB -> 67MB.
// ---------------------------------------------------------------------------
__global__ __launch_bounds__(256) void pv_kernel(
    const float* __restrict__ P, const float* __restrict__ Zpart,
    const float* __restrict__ values, float* __restrict__ out)
{
    __shared__ float ps[4 * 260];
    __shared__ float red[4 * 512];
    const int b  = blockIdx.x >> 6;
    const int q0 = (blockIdx.x & 63) * 4;
    const int t  = threadIdx.x;

    // phase A: p[q][k] = P * (1/Z)  (4 k per thread)
    {
        const int q = t >> 6;
        const int k = (t & 63) * 4;
        const float* zb = Zpart + (size_t)b * 2048 + k;
        float4 z = make_float4(0.f, 0.f, 0.f, 0.f);
        #pragma unroll
        for (int qt = 0; qt < 8; ++qt) {
            float4 a = *(const float4*)(zb + qt * 256);
            z.x += a.x; z.y += a.y; z.z += a.z; z.w += a.w;
        }
        const float* prow = P + ((size_t)(b * 256 + q0 + q)) * 256 + k;
        float4 s = *(const float4*)prow;
        float4 r;
        r.x = s.x * __builtin_amdgcn_rcpf(z.x);
        r.y = s.y * __builtin_amdgcn_rcpf(z.y);
        r.z = s.z * __builtin_amdgcn_rcpf(z.z);
        r.w = s.w * __builtin_amdgcn_rcpf(z.w);
        *(float4*)&ps[q * 260 + k] = r;
    }
    __syncthreads();

    const int wid  = t >> 6;    // k-slice owner: kk in [wid*64, wid*64+64)
    const int lane = t & 63;    // d = lane*2, lane*2+1
    const float* vb = values + (size_t)b * 256 * 128 + lane * 2;

    float ax[4] = {0.f, 0.f, 0.f, 0.f};
    float ay[4] = {0.f, 0.f, 0.f, 0.f};

    for (int kk4 = wid * 16; kk4 < wid * 16 + 16; ++kk4) {
        float4 p0 = *(const float4*)&ps[0 * 260 + kk4 * 4];
        float4 p1 = *(const float4*)&ps[1 * 260 + kk4 * 4];
        float4 p2 = *(const float4*)&ps[2 * 260 + kk4 * 4];
        float4 p3 = *(const float4*)&ps[3 * 260 + kk4 * 4];
        #pragma unroll
        for (int u = 0; u < 4; ++u) {
            int kk = kk4 * 4 + u;
            float2 v = *(const float2*)(vb + (size_t)kk * 128);
            float f0 = (&p0.x)[u], f1 = (&p1.x)[u], f2 = (&p2.x)[u], f3 = (&p3.x)[u];
            ax[0] = fmaf(f0, v.x, ax[0]); ay[0] = fmaf(f0, v.y, ay[0]);
            ax[1] = fmaf(f1, v.x, ax[1]); ay[1] = fmaf(f1, v.y, ay[1]);
            ax[2] = fmaf(f2, v.x, ax[2]); ay[2] = fmaf(f2, v.y, ay[2]);
            ax[3] = fmaf(f3, v.x, ax[3]); ay[3] = fmaf(f3, v.y, ay[3]);
        }
    }

    #pragma unroll
    for (int q = 0; q < 4; ++q)
        *(float2*)&red[wid * 512 + q * 128 + lane * 2] = make_float2(ax[q], ay[q]);
    __syncthreads();

    {
        const int j = t * 2;            // q = j>>7, d = j&127
        float2 s = make_float2(0.f, 0.f);
        #pragma unroll
        for (int w = 0; w < 4; ++w) {
            float2 r = *(const float2*)&red[w * 512 + j];
            s.x += r.x; s.y += r.y;
        }
        const int q = j >> 7, d = j & 127;
        *(float2*)&out[((size_t)(b * 256 + q0 + q)) * 128 + d] = s;
    }
}

// ---------------------------------------------------------------------------
extern "C" void kernel_launch(void* const* d_in, const int* in_sizes, int n_in,
                              void* d_out, int out_size, void* d_ws, size_t ws_size,
                              hipStream_t stream)
{
    const float* queries = (const float*)d_in[0];  // (8,256,128)
    const float* keys    = (const float*)d_in[1];  // (8,256,128)
    const float* values  = (const float*)d_in[2];  // (8,256,128)
    const float* Wq      = (const float*)d_in[3];  // (128,128)
    const float* Wk      = (const float*)d_in[4];  // (128,128)
    const float* wv      = (const float*)d_in[5];  // (128,)
    float* out = (float*)d_out;                    // (8,256,128)

    float* ws = (float*)d_ws;
    float* qp    = ws;                   // 262144 floats (scaled by 2log2e)
    float* kp    = ws + 262144;          // 262144 floats
    float* P     = ws + 524288;          // 524288 floats  exp(s)
    float* Zpart = ws + 1048576;         // 16384 floats
    float* WqT   = ws + 1064960;         // 16384 floats
    float* WkT   = ws + 1081344;         // 16384 floats

    transposeW_kernel<<<32, 256, 0, stream>>>(Wq, Wk, WqT, WkT);
    proj_kernel<<<512, 256, 0, stream>>>(queries, keys, WqT, WkT, qp, kp);
    scoreP_kernel<<<dim3(8, 8, 8), 256, 0, stream>>>(qp, kp, wv, P, Zpart);
    pv_kernel<<<512, 256, 0, stream>>>(P, Zpart, values, out);
}